// Round 14
// baseline (424.554 us; speedup 1.0000x reference)
//
#include <hip/hip_runtime.h>

typedef float          f32x4  __attribute__((ext_vector_type(4)));
typedef short          bf16x8 __attribute__((ext_vector_type(8)));
typedef _Float16       f16x8  __attribute__((ext_vector_type(8)));
typedef unsigned short u16x4  __attribute__((ext_vector_type(4)));

static constexpr int kBS = 16;
static constexpr int kHW = 1024;

__device__ __forceinline__ unsigned short f2bf(float x) {
  union { float f; unsigned int u; } v; v.f = x;
  unsigned int r = v.u + 0x7fffu + ((v.u >> 16) & 1u);
  return (unsigned short)(r >> 16);
}
__device__ __forceinline__ float bf2f(unsigned short h) {
  union { unsigned int u; float f; } v; v.u = ((unsigned int)h) << 16;
  return v.f;
}
__device__ __forceinline__ unsigned short h2u(_Float16 h) {
  union { _Float16 h; unsigned short u; } v; v.h = h; return v.u;
}

// 2-plane fp16 split with 4096-scaled residual: x ~= p0 + p1/4096.
__device__ __forceinline__ void split2h(float x, unsigned short& u0, unsigned short& u1) {
  _Float16 h0 = (_Float16)x;
  if (fabsf(x) < 6.1035156e-05f) h0 = (_Float16)0.f;
  const float r = (x - (float)h0) * 4096.f;
  u0 = h2u(h0);
  u1 = h2u((_Float16)r);
}

// ---------------------------------------------------------------------------
// fp32 -> 2 fp16 planes (scaled-residual), vectorized
// ---------------------------------------------------------------------------
__global__ __launch_bounds__(256)
void split_act2h(const f32x4* __restrict__ X, u16x4* __restrict__ P0,
                 u16x4* __restrict__ P1, int n4)
{
  int i = blockIdx.x * 256 + threadIdx.x;
  if (i >= n4) return;
  f32x4 x = X[i];
  u16x4 s0, s1;
#pragma unroll
  for (int u = 0; u < 4; ++u) {
    unsigned short a, b;
    split2h(x[u], a, b);
    s0[u] = a; s1[u] = b;
  }
  P0[i] = s0; P1[i] = s1;
}

// W [K][N] fp32 -> 2 fp16 planes of W^T [N][K]
__global__ __launch_bounds__(256)
void split_wT2h(const float* __restrict__ Wm, unsigned short* __restrict__ T0,
                unsigned short* __restrict__ T1, int K, int N)
{
  __shared__ float ts[32][33];
  const int k0 = blockIdx.x * 32, n0 = blockIdx.y * 32;
  const int tx = threadIdx.x, ty = threadIdx.y;   // 32 x 8
#pragma unroll
  for (int r = 0; r < 4; ++r)
    ts[ty + r * 8][tx] = Wm[(size_t)(k0 + ty + r * 8) * N + n0 + tx];
  __syncthreads();
#pragma unroll
  for (int r = 0; r < 4; ++r) {
    const int n = ty + r * 8;
    const size_t off = (size_t)(n0 + n) * K + k0 + tx;
    unsigned short a, b;
    split2h(ts[tx][n], a, b);
    T0[off] = a; T1[off] = b;
  }
}

// W [K][N] fp32 -> 1 plane of W^T (bf16 or fp16)
template<bool F16>
__global__ __launch_bounds__(256)
void split_wT1(const float* __restrict__ Wm, unsigned short* __restrict__ T0,
               int K, int N)
{
  __shared__ float ts[32][33];
  const int k0 = blockIdx.x * 32, n0 = blockIdx.y * 32;
  const int tx = threadIdx.x, ty = threadIdx.y;
#pragma unroll
  for (int r = 0; r < 4; ++r)
    ts[ty + r * 8][tx] = Wm[(size_t)(k0 + ty + r * 8) * N + n0 + tx];
  __syncthreads();
#pragma unroll
  for (int r = 0; r < 4; ++r) {
    const int n = ty + r * 8;
    const float x = ts[tx][n];
    const size_t off = (size_t)(n0 + n) * K + k0 + tx;
    T0[off] = F16 ? h2u((_Float16)x) : f2bf(x);
  }
}

// ---------------------------------------------------------------------------
// Staging (4-wave blocks): one 128x32 16-bit tile, global (involution
// pre-swizzled cols) -> linear LDS via global_load_lds(16B). 2 loads/wave.
// ---------------------------------------------------------------------------
__device__ __forceinline__ void stage_tile(const unsigned short* src, int K,
                                           unsigned short* ldst, int wv, int lane)
{
#pragma unroll
  for (int i = 0; i < 2; ++i) {
    const int s   = wv * 128 + i * 64 + lane;
    const int row = s >> 2;
    const int gc  = ((s & 3) ^ ((row >> 1) & 3)) * 8;
    __builtin_amdgcn_global_load_lds(
        (const __attribute__((address_space(1))) void*)(src + (size_t)row * K + gc),
        (__attribute__((address_space(3))) void*)(ldst + ((wv * 128 + i * 64) << 3)),
        16, 0, 0);
  }
}

// Staging (8-wave blocks): one 256x32 tile (16 KB = 1024 slots), 2 loads/wave.
__device__ __forceinline__ void stage_tile256(const unsigned short* src, int K,
                                              unsigned short* ldst, int wv, int lane)
{
#pragma unroll
  for (int i = 0; i < 2; ++i) {
    const int s   = i * 512 + wv * 64 + lane;
    const int row = s >> 2;
    const int gc  = ((s & 3) ^ ((row >> 1) & 3)) * 8;
    __builtin_amdgcn_global_load_lds(
        (const __attribute__((address_space(1))) void*)(src + (size_t)row * K + gc),
        (__attribute__((address_space(3))) void*)(ldst + ((i * 512 + wv * 64) << 3)),
        16, 0, 0);
  }
}

// ---------------------------------------------------------------------------
// 256x256-tile single-pass GEMM, 512 threads / 8 waves (2M x 4N), per-wave
// 128x64 output (acc[8][4]). BK=32, 2-deep dbuf LDS (2 x 32 KB), counted
// vmcnt(4). Halves LDS traffic per FLOP vs the 128x128/4-wave engine
// (fragment-read duplication A:4-of-8 B:2-of-8 over 4x the FLOPs).
// OUTM: 0=f32, 3=bf16. A [M][K], B [N][K]; z-batched via sA/sB/sC.
// ---------------------------------------------------------------------------
template<int OUTM, bool BIAS, bool RELU>
__global__ __launch_bounds__(512)
void gk256(const unsigned short* __restrict__ A0, const unsigned short* __restrict__ B0,
           const float* __restrict__ bias,
           float* __restrict__ Cf, unsigned short* __restrict__ O0,
           int K, int ldc, long sA, long sB, long sC, float scale)
{
  extern __shared__ __align__(16) unsigned short lds[];   // [2][2][8192]

  const int tid  = threadIdx.x;
  const int wv   = tid >> 6, lane = tid & 63;
  const int wr   = wv >> 2,  wc   = wv & 3;
  const int cr   = lane & 15, cg  = lane >> 4;
  const int bm   = blockIdx.x * 256, bn = blockIdx.y * 256;

  const unsigned short* Ap = A0 + (size_t)blockIdx.z * (size_t)sA + (size_t)bm * K;
  const unsigned short* Bp = B0 + (size_t)blockIdx.z * (size_t)sB + (size_t)bn * K;
  const size_t zC = (size_t)blockIdx.z * (size_t)sC;

  f32x4 acc[8][4];
#pragma unroll
  for (int i = 0; i < 8; ++i)
#pragma unroll
    for (int j = 0; j < 4; ++j)
#pragma unroll
      for (int r = 0; r < 4; ++r) acc[i][j][r] = 0.f;

#define STAGE256(kt, buf)                                                      \
  {                                                                            \
    stage_tile256(Ap + (kt) * 32, K, lds + (size_t)(buf) * 16384,       wv, lane); \
    stage_tile256(Bp + (kt) * 32, K, lds + (size_t)(buf) * 16384 + 8192, wv, lane); \
  }

  const int nt = K >> 5;
  STAGE256(0, 0);
  if (nt > 1) STAGE256(1, 1);

  for (int kt = 0; kt < nt; ++kt) {
    if (kt + 1 < nt) asm volatile("s_waitcnt vmcnt(4)" ::: "memory");
    else             asm volatile("s_waitcnt vmcnt(0)" ::: "memory");
    __builtin_amdgcn_sched_barrier(0);
    __builtin_amdgcn_s_barrier();        // staging for buf landed (all waves)

    const unsigned short* lb = lds + (size_t)(kt & 1) * 16384;
    bf16x8 af[8], bf[4];
#pragma unroll
    for (int f = 0; f < 8; ++f) {
      const int ra = wr * 128 + f * 16 + cr;
      af[f] = *(const bf16x8*)&lb[(ra * 4 + (cg ^ ((ra >> 1) & 3))) * 8];
    }
#pragma unroll
    for (int f = 0; f < 4; ++f) {
      const int rb = wc * 64 + f * 16 + cr;
      bf[f] = *(const bf16x8*)&lb[8192 + (rb * 4 + (cg ^ ((rb >> 1) & 3))) * 8];
    }
#pragma unroll
    for (int i = 0; i < 8; ++i)
#pragma unroll
      for (int j = 0; j < 4; ++j)
        acc[i][j] = __builtin_amdgcn_mfma_f32_16x16x32_bf16(af[i], bf[j], acc[i][j], 0, 0, 0);

    __builtin_amdgcn_s_barrier();        // all readers of buf done
    __builtin_amdgcn_sched_barrier(0);
    if (kt + 2 < nt) STAGE256(kt + 2, kt & 1);
  }
#undef STAGE256

  float* CfB = Cf + zC;
  unsigned short* O0B = O0 + zC;
#pragma unroll
  for (int fm = 0; fm < 8; ++fm) {
#pragma unroll
    for (int fn = 0; fn < 4; ++fn) {
      const int n  = bn + wc * 64 + fn * 16 + cr;
      const int m0 = bm + wr * 128 + fm * 16 + 4 * cg;
      float bv = 0.f;
      if (BIAS) bv = bias[n];
      f32x4 v = acc[fm][fn];
#pragma unroll
      for (int r = 0; r < 4; ++r) {
        float x = v[r] * scale + bv;
        if (RELU) x = fmaxf(x, 0.f);
        const size_t off = (size_t)(m0 + r) * ldc + n;
        if (OUTM == 0) CfB[off] = x;
        else O0B[off] = f2bf(x);
      }
    }
  }
}

// ---------------------------------------------------------------------------
// Unified 128x128 MFMA GEMM engine (proven r9/r10 structure). 4 waves, BK=32,
// KU K-tiles/phase, DEPTH-deep circular dbuf with counted vmcnt.
//  ORD0: 1-pass;  ORD1: fp16 scaled-residual 2-plane, 3 passes.
// OUTM: 0=f32, 1=2 fp16 planes, 2=f32+2 fp16 planes, 3=bf16,
//       4=bf16 transposed ([N][M], stride ldc).
// ---------------------------------------------------------------------------
template<int ORD, int KU, int DEPTH, int OUTM, bool BIAS, bool RELU, bool F16IN>
__global__ __launch_bounds__(256)
void gke(const unsigned short* __restrict__ A0, const unsigned short* __restrict__ A1,
         const unsigned short* __restrict__ B0, const unsigned short* __restrict__ B1,
         const float* __restrict__ bias,
         float* __restrict__ Cf, unsigned short* __restrict__ O0,
         unsigned short* __restrict__ O1,
         int K, int ldc, long sA, long sB, long sC, long sBias, float scale)
{
  constexpr int NP   = ORD + 1;
  constexpr int NT   = 2 * NP;
  constexpr int TPP  = KU * NT;                // tiles per phase
  constexpr int LPP  = TPP * 2;                // loads per wave per phase
  static_assert(DEPTH == 2 || DEPTH == 4, "DEPTH in {2,4}");
  static_assert(LPP == 4 || LPP == 8 || LPP == 16, "vmcnt literals");
  extern __shared__ __align__(16) unsigned short lds[];

  const int tid  = threadIdx.x;
  const int wv   = tid >> 6, lane = tid & 63;
  const int wr   = wv >> 1,  wc   = wv & 1;
  const int cr   = lane & 15, cg  = lane >> 4;
  const int bm   = blockIdx.x * 128, bn = blockIdx.y * 128;

  const size_t zA = (size_t)blockIdx.z * (size_t)sA;
  const size_t zB = (size_t)blockIdx.z * (size_t)sB;
  const size_t zC = (size_t)blockIdx.z * (size_t)sC;
  const size_t zBias = (size_t)blockIdx.z * (size_t)sBias;

  const unsigned short* srcs[NT];
  srcs[0] = A0 + zA + (size_t)bm * K;
  if (NP == 2) srcs[1] = A1 + zA + (size_t)bm * K;
  srcs[NP + 0] = B0 + zB + (size_t)bn * K;
  if (NP == 2) srcs[NP + 1] = B1 + zB + (size_t)bn * K;

  f32x4 acc0[4][4], acc1[4][4];
#pragma unroll
  for (int i = 0; i < 4; ++i)
#pragma unroll
    for (int j = 0; j < 4; ++j)
#pragma unroll
      for (int r = 0; r < 4; ++r) {
        acc0[i][j][r] = 0.f;
        if (ORD == 1) acc1[i][j][r] = 0.f;
      }

#define STAGE_PH(ph, buf)                                                       \
  {                                                                             \
    _Pragma("unroll")                                                           \
    for (int u = 0; u < KU; ++u)                                                \
      _Pragma("unroll")                                                         \
      for (int t = 0; t < NT; ++t)                                              \
        stage_tile(srcs[t] + ((ph) * KU + u) * 32, K,                           \
                   lds + (size_t)((buf) * TPP + u * NT + t) * 4096, wv, lane);  \
  }
#define LOADA(u, pa)                                                            \
  {                                                                             \
    _Pragma("unroll")                                                           \
    for (int f = 0; f < 4; ++f) {                                               \
      const int ra = wr * 64 + f * 16 + cr;                                     \
      af[f] = *(const bf16x8*)&lb[(size_t)((u) * NT + (pa)) * 4096 +            \
                                  (ra * 4 + (cg ^ ((ra >> 1) & 3))) * 8];       \
    }                                                                           \
  }
#define DOPB(u, pb, ACC)                                                        \
  {                                                                             \
    bf16x8 bfr[4];                                                              \
    _Pragma("unroll")                                                           \
    for (int f = 0; f < 4; ++f) {                                               \
      const int rb = wc * 64 + f * 16 + cr;                                     \
      bfr[f] = *(const bf16x8*)&lb[(size_t)((u) * NT + NP + (pb)) * 4096 +      \
                                   (rb * 4 + (cg ^ ((rb >> 1) & 3))) * 8];      \
    }                                                                           \
    _Pragma("unroll")                                                           \
    for (int i = 0; i < 4; ++i)                                                 \
      _Pragma("unroll")                                                         \
      for (int j = 0; j < 4; ++j) {                                             \
        if constexpr (F16IN)                                                    \
          ACC[i][j] = __builtin_amdgcn_mfma_f32_16x16x32_f16(                   \
              __builtin_bit_cast(f16x8, af[i]), __builtin_bit_cast(f16x8, bfr[j]), \
              ACC[i][j], 0, 0, 0);                                              \
        else                                                                    \
          ACC[i][j] = __builtin_amdgcn_mfma_f32_16x16x32_bf16(af[i], bfr[j],    \
              ACC[i][j], 0, 0, 0);                                              \
      }                                                                         \
  }
#define COMPUTE_PH(buf)                                                         \
  {                                                                             \
    const unsigned short* lb = lds + (size_t)(buf) * TPP * 4096;                \
    bf16x8 af[4];                                                               \
    _Pragma("unroll")                                                           \
    for (int u = 0; u < KU; ++u) {                                              \
      if constexpr (ORD == 1) {                                                 \
        LOADA(u, 0); DOPB(u, 0, acc0); DOPB(u, 1, acc1);                        \
        LOADA(u, 1); DOPB(u, 0, acc1);                                          \
      } else {                                                                  \
        LOADA(u, 0); DOPB(u, 0, acc0);                                          \
      }                                                                         \
    }                                                                           \
  }

  const int nph = K / (32 * KU);
#pragma unroll
  for (int d = 0; d < DEPTH; ++d)
    if (d < nph) STAGE_PH(d, d);

  for (int ph = 0; ph < nph; ++ph) {
    const int rem = nph - 1 - ph;
    const int fut = rem < (DEPTH - 1) ? rem : (DEPTH - 1);
    if constexpr (LPP == 4) {
      if (fut >= 3)      asm volatile("s_waitcnt vmcnt(12)" ::: "memory");
      else if (fut == 2) asm volatile("s_waitcnt vmcnt(8)" ::: "memory");
      else if (fut == 1) asm volatile("s_waitcnt vmcnt(4)" ::: "memory");
      else               asm volatile("s_waitcnt vmcnt(0)" ::: "memory");
    } else if constexpr (LPP == 8) {
      if (fut >= 3)      asm volatile("s_waitcnt vmcnt(24)" ::: "memory");
      else if (fut == 2) asm volatile("s_waitcnt vmcnt(16)" ::: "memory");
      else if (fut == 1) asm volatile("s_waitcnt vmcnt(8)" ::: "memory");
      else               asm volatile("s_waitcnt vmcnt(0)" ::: "memory");
    } else {
      if (fut >= 1)      asm volatile("s_waitcnt vmcnt(16)" ::: "memory");
      else               asm volatile("s_waitcnt vmcnt(0)" ::: "memory");
    }
    __builtin_amdgcn_sched_barrier(0);
    __builtin_amdgcn_s_barrier();        // all waves' stores for buf landed
    COMPUTE_PH(ph & (DEPTH - 1));
    __builtin_amdgcn_s_barrier();        // all readers of buf done
    __builtin_amdgcn_sched_barrier(0);
    if (ph + DEPTH < nph) STAGE_PH(ph + DEPTH, ph & (DEPTH - 1));
  }
#undef STAGE_PH
#undef LOADA
#undef DOPB
#undef COMPUTE_PH

  // epilogue: C/D layout col = lane&15, row = 4*(lane>>4)+reg  [m89-verified]
  const float RS = 2.44140625e-4f;       // 1/4096
  float* CfB = Cf + zC;
  unsigned short* O0B = O0 + zC;
  unsigned short* O1B = O1 + zC;
#pragma unroll
  for (int fm = 0; fm < 4; ++fm) {
#pragma unroll
    for (int fn = 0; fn < 4; ++fn) {
      const int n  = bn + wc * 64 + fn * 16 + cr;
      const int m0 = bm + wr * 64 + fm * 16 + 4 * cg;
      float bv = 0.f;
      if (BIAS) bv = bias[zBias + n];
      if (OUTM == 4) {
        u16x4 o;
#pragma unroll
        for (int r = 0; r < 4; ++r) {
          float x = acc0[fm][fn][r];
          if constexpr (ORD == 1) x += acc1[fm][fn][r] * RS;
          x = x * scale + bv;
          if (RELU) x = fmaxf(x, 0.f);
          o[r] = f2bf(x);
        }
        *(u16x4*)(O0B + (size_t)n * ldc + m0) = o;
      } else {
#pragma unroll
        for (int r = 0; r < 4; ++r) {
          float x = acc0[fm][fn][r];
          if constexpr (ORD == 1) x += acc1[fm][fn][r] * RS;
          x = x * scale + bv;
          if (RELU) x = fmaxf(x, 0.f);
          const size_t off = (size_t)(m0 + r) * ldc + n;
          if (OUTM == 0) CfB[off] = x;
          else if (OUTM == 3) O0B[off] = f2bf(x);
          else {
            unsigned short a, b;
            split2h(x, a, b);
            O0B[off] = a; O1B[off] = b;
            if (OUTM == 2) CfB[off] = x;
          }
        }
      }
    }
  }
}

// ---------------------------------------------------------------------------
// Row argmax over rows of length 256 (np.argmax first-max tie rule).
// 4 waves/block, one row per wave.
// ---------------------------------------------------------------------------
__global__ __launch_bounds__(256)
void row_argmax4(const float* __restrict__ X, int* __restrict__ out)
{
  const int row = blockIdx.x * 4 + (threadIdx.x >> 6);
  const float* xr = X + (size_t)row * 256;
  const int lane = threadIdx.x & 63;
  float best = -3.0e38f;
  int bi = 0;
#pragma unroll
  for (int t = 0; t < 4; ++t) {
    const int a = lane + (t << 6);
    const float x = xr[a];
    if (x > best) { best = x; bi = a; }
  }
#pragma unroll
  for (int off = 32; off >= 1; off >>= 1) {
    const float ov = __shfl_xor(best, off);
    const int   oi = __shfl_xor(bi, off);
    if (ov > best || (ov == best && oi < bi)) { best = ov; bi = oi; }
  }
  if (lane == 0) out[row] = bi;
}

// ---------------------------------------------------------------------------
// Masked softmax over rows of length 1024 for a 512-row i-half; emits
// P^T[b][j][i_global] bf16. Lg layout [b][512][1024].
// ---------------------------------------------------------------------------
__global__ __launch_bounds__(256)
void softmax_T(const float* __restrict__ Lg, const int* __restrict__ aidx,
               const int* __restrict__ bidx, unsigned short* __restrict__ PT,
               int ihalf)
{
  __shared__ int bj[1024];
  __shared__ unsigned short tile[1024 * 17];
  const int tid = threadIdx.x;
  const int i0  = blockIdx.x * 16;          // 0..511
  const int b   = blockIdx.y;
  const int r   = tid >> 4;
  const int l16 = tid & 15;

  for (int j = tid; j < 1024; j += 256) bj[j] = bidx[(b << 10) + j];
  __syncthreads();

  const int ai  = aidx[(b << 10) + (ihalf << 9) + i0 + r];
  const float* Lr = Lg + ((size_t)b * 512 + i0 + r) * 1024;
  const int jb = l16 * 64;

  float x[64];
  float mx = -3.0e38f;
#pragma unroll
  for (int q = 0; q < 16; ++q) {
    f32x4 f = *(const f32x4*)(Lr + jb + (q << 2));
#pragma unroll
    for (int u = 0; u < 4; ++u) {
      const int j = jb + (q << 2) + u;
      float t = f[u];
      if (bj[j] != ai) t -= 1e6f;
      x[(q << 2) + u] = t;
      mx = fmaxf(mx, t);
    }
  }
#pragma unroll
  for (int off = 8; off >= 1; off >>= 1) mx = fmaxf(mx, __shfl_xor(mx, off));
  float s = 0.f;
#pragma unroll
  for (int k = 0; k < 64; ++k) { float e = expf(x[k] - mx); x[k] = e; s += e; }
#pragma unroll
  for (int off = 8; off >= 1; off >>= 1) s += __shfl_xor(s, off);
  const float inv = 1.f / s;

#pragma unroll
  for (int k = 0; k < 64; ++k)
    tile[(jb + k) * 17 + r] = f2bf(x[k] * inv);
  __syncthreads();

  for (int j = tid; j < 1024; j += 256) {
    const unsigned short* tp = &tile[j * 17];
    unsigned int w[8];
#pragma unroll
    for (int q = 0; q < 8; ++q)
      w[q] = (unsigned int)tp[2 * q] | ((unsigned int)tp[2 * q + 1] << 16);
    const size_t off = ((size_t)b << 20) + ((size_t)j << 10) + (ihalf << 9) + i0;
    unsigned int* dst = (unsigned int*)(PT + off);
    *(uint4*)dst       = make_uint4(w[0], w[1], w[2], w[3]);
    *((uint4*)dst + 1) = make_uint4(w[4], w[5], w[6], w[7]);
  }
}

// ---------------------------------------------------------------------------
extern "C" void kernel_launch(void* const* d_in, const int* in_sizes, int n_in,
                              void* d_out, int out_size, void* d_ws, size_t ws_size,
                              hipStream_t stream)
{
  (void)in_sizes; (void)n_in; (void)out_size; (void)ws_size;

  const float* tok  = (const float*)d_in[0];
  const float* supp = (const float*)d_in[1];
  const float* qry  = (const float*)d_in[2];
  const float* W_qa = (const float*)d_in[3];
  const float* b_qa = (const float*)d_in[4];
  const float* W_ks = (const float*)d_in[5];
  const float* b_ks = (const float*)d_in[6];
  const float* W_ka = (const float*)d_in[7];
  const float* b_ka = (const float*)d_in[8];
  const float* W_vs = (const float*)d_in[9];
  const float* b_vs = (const float*)d_in[10];
  const float* W_f1 = (const float*)d_in[11];
  const float* b_f1 = (const float*)d_in[12];
  const float* W_f2 = (const float*)d_in[13];
  const float* b_f2 = (const float*)d_in[14];

  // ORD1 engines: proven depth-2. ORD0 small: r10 config (32 KB, depth-2).
  // Large 1-pass GEMMs (PV/FFN1/FFN2): new 256^2 8-wave engine (64 KB).
  auto kProj  = &gke<1,1,2,1,true ,false,true >;   // 64 KB, vmcnt(8)
  auto kScore = &gke<1,2,2,2,false,false,true >;   // 128 KB, vmcnt(16)
  auto kLogit = &gke<1,1,2,0,false,false,true >;   // 64 KB
  auto kVsT   = &gke<0,1,2,4,true ,false,true >;   // 32 KB fp16 1-pass
  auto kPV    = &gk256<3,false,false>;             // 64 KB 256^2
  auto kFFN1  = &gk256<3,true ,true >;             // 64 KB 256^2
  auto kFFN2  = &gk256<0,true ,false>;             // 64 KB 256^2
  hipFuncSetAttribute((const void*)kProj,  hipFuncAttributeMaxDynamicSharedMemorySize, 65536);
  hipFuncSetAttribute((const void*)kScore, hipFuncAttributeMaxDynamicSharedMemorySize, 131072);
  hipFuncSetAttribute((const void*)kLogit, hipFuncAttributeMaxDynamicSharedMemorySize, 65536);
  hipFuncSetAttribute((const void*)kVsT,   hipFuncAttributeMaxDynamicSharedMemorySize, 32768);
  hipFuncSetAttribute((const void*)kPV,    hipFuncAttributeMaxDynamicSharedMemorySize, 65536);
  hipFuncSetAttribute((const void*)kFFN1,  hipFuncAttributeMaxDynamicSharedMemorySize, 65536);
  hipFuncSetAttribute((const void*)kFFN2,  hipFuncAttributeMaxDynamicSharedMemorySize, 65536);

  char* W = (char*)d_ws;
  constexpr size_t MiB = 1048576;
  auto U = [&](double off) { return (unsigned short*)(W + (size_t)(off * MiB)); };
  auto F = [&](double off) { return (float*)(W + (size_t)(off * MiB)); };
  auto I = [&](double off) { return (int*)(W + (size_t)(off * MiB)); };

  // lifetimes (MiB), round-6-audited layout (2-plane subset):
  // @0 tokP{0,4} -> QTF -> suppP0 -> SAF -> PT(0-32)
  // @16 WQAT{16,16.5}, WKAT{17.5,18}, WKST{19,19.5}, WVST{20.5}
  // @22 qaP{22,26} | dec@32-48 | @34 kaP{34,38}
  // @46 qryP{46,62} -> QTP{46,54} | suppP1@62 -> vsT@62 | SAP{78,86}
  // @94 qqP{94,110} -> ksP -> Lg(94-126) | mid@62-110 | WF@142 | bias@148 idx@150
  const double oTOK0=0, oTOK1=4, oQTF=0, oSUP0=0, oSAF=0, oPT=0;
  const double oWQAT=16, oWKAT=17.5, oWKST=19, oWVST=20.5;
  const double oQA0=22, oQA1=26, oDEC=32, oKA0=34, oKA1=38;
  const double oQRY0=46, oQRY1=62, oQTP0=46, oQTP1=54;
  const double oSUP1=62, oVST=62, oSAP0=78, oSAP1=86;
  const double oQQ0=94, oQQ1=110, oLG=94, oMID=62;
  const double oWF1=142, oWF2=143.5, oBIA=148, oIDXB=150, oIDXA=150.0625;
  const double hP = 0.5;  // one 512x512 16-bit plane = 0.5 MiB

  const dim3 B256(256), B512(512), BW(32, 8);
  float* dummyF = F(oLG);
  unsigned short* dummyU = U(oLG);

  // S0: stage qa/ka biases adjacently for the merged dual launch
  hipMemcpyAsync(W + (size_t)(oBIA * MiB), b_qa, 2048, hipMemcpyDeviceToDevice, stream);
  hipMemcpyAsync(W + (size_t)(oBIA * MiB) + 2048, b_ka, 2048, hipMemcpyDeviceToDevice, stream);

  // S1: weight + tok splits
  split_wT2h<<<dim3(16,16), BW, 0, stream>>>(W_qa, U(oWQAT), U(oWQAT+hP), 512, 512);
  split_wT2h<<<dim3(16,16), BW, 0, stream>>>(W_ka, U(oWKAT), U(oWKAT+hP), 512, 512);
  split_wT2h<<<dim3(16,16), BW, 0, stream>>>(W_ks, U(oWKST), U(oWKST+hP), 512, 512);
  split_wT1<true><<<dim3(16,16), BW, 0, stream>>>(W_vs, U(oWVST), 512, 512);
  split_act2h<<<dim3(2048), B256, 0, stream>>>((const f32x4*)tok, (u16x4*)U(oTOK0), (u16x4*)U(oTOK1), 524288);
  // S2: qa|ka merged projection: z=0 -> {WQAT,b_qa,qaP}, z=1 -> {WKAT,b_ka,kaP}
  kProj<<<dim3(32,4,2), B256, 65536, stream>>>(
      U(oTOK0),U(oTOK1), U(oWQAT),U(oWQAT+hP),
      F(oBIA), dummyF, U(oQA0),U(oQA1), 512, 512, 0, 786432, 6291456, 512, 1.f);
  // S3: qry split
  split_act2h<<<dim3(8192), B256, 0, stream>>>((const f32x4*)qry, (u16x4*)U(oQRY0), (u16x4*)U(oQRY1), 2097152);
  // S4: qq projection
  kProj<<<dim3(128,4,1), B256, 65536, stream>>>(
      U(oQRY0),U(oQRY1), U(oWQAT),U(oWQAT+hP),
      b_qa, dummyF, U(oQQ0),U(oQQ1), 512, 512, 0,0,0,0, 1.f);
  // S5: qt score = qq . ka^T / 8  -> f32 (QTF@0) + 2 fp16 planes (QTP)
  kScore<<<dim3(8,2,16), B256, 131072, stream>>>(
      U(oQQ0),U(oQQ1), U(oKA0),U(oKA1),
      nullptr, F(oQTF), U(oQTP0),U(oQTP1), 512, 256,
      524288, 131072, 262144, 0, 0.125f);
  row_argmax4<<<dim3(kBS * kHW / 4), B256, 0, stream>>>(F(oQTF), I(oIDXB));
  // S6: supp split (plane0 over dead QTF region; plane1 over dead qry plane1)
  split_act2h<<<dim3(8192), B256, 0, stream>>>((const f32x4*)supp, (u16x4*)U(oSUP0), (u16x4*)U(oSUP1), 2097152);
  // S7: ks projection (out over dead qq planes), then vs^T (reads supp plane0)
  kProj<<<dim3(128,4,1), B256, 65536, stream>>>(
      U(oSUP0),U(oSUP1), U(oWKST),U(oWKST+hP),
      b_ks, dummyF, U(oQQ0),U(oQQ1), 512, 512, 0,0,0,0, 1.f);
  kVsT<<<dim3(8,4,16), B256, 32768, stream>>>(
      U(oSUP0),dummyU, U(oWVST),dummyU,
      b_vs, dummyF, U(oVST),dummyU, 512, 1024,
      524288, 0, 524288, 0, 1.f);
  // S8: sa score = ks . qa^T / 8  (SAF@0: supp plane0 dead after vsT)
  kScore<<<dim3(8,2,16), B256, 131072, stream>>>(
      U(oQQ0),U(oQQ1), U(oQA0),U(oQA1),
      nullptr, F(oSAF), U(oSAP0),U(oSAP1), 512, 256,
      524288, 131072, 262144, 0, 0.125f);
  row_argmax4<<<dim3(kBS * kHW / 4), B256, 0, stream>>>(F(oSAF), I(oIDXA));
  // FFN weight splits (bf16, stable through the end)
  split_wT1<false><<<dim3(16,48), BW, 0, stream>>>(W_f1, U(oWF1), 512, 1536);
  split_wT1<false><<<dim3(48,16), BW, 0, stream>>>(W_f2, U(oWF2), 1536, 512);
  // S9/S10: logits halves (fp16 2-plane 3-pass, K=256) + masked softmax -> P^T
  for (int h = 0; h < 2; ++h) {
    kLogit<<<dim3(4,8,16), B256, 65536, stream>>>(
        U(oSAP0) + (size_t)h*512*256, U(oSAP1) + (size_t)h*512*256,
        U(oQTP0), U(oQTP1),
        nullptr, F(oLG), dummyU,dummyU, 256, 1024,
        262144, 262144, 524288, 0, 1.f);
    softmax_T<<<dim3(32,16), B256, 0, stream>>>(F(oLG), I(oIDXA), I(oIDXB), U(oPT), h);
  }
  // S11: dec = P^T . vs   (A=PT [j][i], B=vsT [c][i], bf16, K=1024, 256^2)
  kPV<<<dim3(4,2,16), B512, 65536, stream>>>(
      U(oPT), U(oVST), nullptr, dummyF, U(oDEC), 1024, 512,
      1048576, 524288, 524288, 1.f);
  // S12: FFN1 = relu(dec @ W_f1 + b1) -> bf16 (256^2)
  kFFN1<<<dim3(64,6,1), B512, 65536, stream>>>(
      U(oDEC), U(oWF1), b_f1, dummyF, U(oMID), 512, 1536, 0,0,0, 1.f);
  // S13: FFN2 = mid @ W_f2 + b2 -> d_out fp32 (K=1536, 256^2)
  kFFN2<<<dim3(64,2,1), B512, 65536, stream>>>(
      U(oMID), U(oWF2), b_f2, (float*)d_out, dummyU, 1536, 512, 0,0,0, 1.f);
}

// Round 15
// 407.097 us; speedup vs baseline: 1.0429x; 1.0429x over previous
//
#include <hip/hip_runtime.h>

typedef float          f32x4  __attribute__((ext_vector_type(4)));
typedef short          bf16x8 __attribute__((ext_vector_type(8)));
typedef _Float16       f16x8  __attribute__((ext_vector_type(8)));
typedef unsigned short u16x4  __attribute__((ext_vector_type(4)));

static constexpr int kBS = 16;
static constexpr int kHW = 1024;

__device__ __forceinline__ unsigned short f2bf(float x) {
  union { float f; unsigned int u; } v; v.f = x;
  unsigned int r = v.u + 0x7fffu + ((v.u >> 16) & 1u);
  return (unsigned short)(r >> 16);
}
__device__ __forceinline__ float bf2f(unsigned short h) {
  union { unsigned int u; float f; } v; v.u = ((unsigned int)h) << 16;
  return v.f;
}
__device__ __forceinline__ unsigned short h2u(_Float16 h) {
  union { _Float16 h; unsigned short u; } v; v.h = h; return v.u;
}
// order-preserving f32 -> u32 (finite floats): f1<f2 <=> mono(f1)<mono(f2)
__device__ __forceinline__ unsigned int fmono(float f) {
  union { float f; unsigned int u; } v; v.f = f;
  return (v.u & 0x80000000u) ? ~v.u : (v.u | 0x80000000u);
}

// 2-plane fp16 split with 4096-scaled residual: x ~= p0 + p1/4096.
__device__ __forceinline__ void split2h(float x, unsigned short& u0, unsigned short& u1) {
  _Float16 h0 = (_Float16)x;
  if (fabsf(x) < 6.1035156e-05f) h0 = (_Float16)0.f;
  const float r = (x - (float)h0) * 4096.f;
  u0 = h2u(h0);
  u1 = h2u((_Float16)r);
}

// ---------------------------------------------------------------------------
// fp32 -> 2 fp16 planes (scaled-residual), vectorized
// ---------------------------------------------------------------------------
__global__ __launch_bounds__(256)
void split_act2h(const f32x4* __restrict__ X, u16x4* __restrict__ P0,
                 u16x4* __restrict__ P1, int n4)
{
  int i = blockIdx.x * 256 + threadIdx.x;
  if (i >= n4) return;
  f32x4 x = X[i];
  u16x4 s0, s1;
#pragma unroll
  for (int u = 0; u < 4; ++u) {
    unsigned short a, b;
    split2h(x[u], a, b);
    s0[u] = a; s1[u] = b;
  }
  P0[i] = s0; P1[i] = s1;
}

// W [K][N] fp32 -> 2 fp16 planes of W^T [N][K]
__global__ __launch_bounds__(256)
void split_wT2h(const float* __restrict__ Wm, unsigned short* __restrict__ T0,
                unsigned short* __restrict__ T1, int K, int N)
{
  __shared__ float ts[32][33];
  const int k0 = blockIdx.x * 32, n0 = blockIdx.y * 32;
  const int tx = threadIdx.x, ty = threadIdx.y;   // 32 x 8
#pragma unroll
  for (int r = 0; r < 4; ++r)
    ts[ty + r * 8][tx] = Wm[(size_t)(k0 + ty + r * 8) * N + n0 + tx];
  __syncthreads();
#pragma unroll
  for (int r = 0; r < 4; ++r) {
    const int n = ty + r * 8;
    const size_t off = (size_t)(n0 + n) * K + k0 + tx;
    unsigned short a, b;
    split2h(ts[tx][n], a, b);
    T0[off] = a; T1[off] = b;
  }
}

// W [K][N] fp32 -> 1 plane of W^T (bf16 or fp16)
template<bool F16>
__global__ __launch_bounds__(256)
void split_wT1(const float* __restrict__ Wm, unsigned short* __restrict__ T0,
               int K, int N)
{
  __shared__ float ts[32][33];
  const int k0 = blockIdx.x * 32, n0 = blockIdx.y * 32;
  const int tx = threadIdx.x, ty = threadIdx.y;
#pragma unroll
  for (int r = 0; r < 4; ++r)
    ts[ty + r * 8][tx] = Wm[(size_t)(k0 + ty + r * 8) * N + n0 + tx];
  __syncthreads();
#pragma unroll
  for (int r = 0; r < 4; ++r) {
    const int n = ty + r * 8;
    const float x = ts[tx][n];
    const size_t off = (size_t)(n0 + n) * K + k0 + tx;
    T0[off] = F16 ? h2u((_Float16)x) : f2bf(x);
  }
}

// ---------------------------------------------------------------------------
// Staging: one 128x32 16-bit tile, global (involution pre-swizzled cols) ->
// linear LDS via global_load_lds(16B). 2 loads per wave per tile.
// ---------------------------------------------------------------------------
__device__ __forceinline__ void stage_tile(const unsigned short* src, int K,
                                           unsigned short* ldst, int wv, int lane)
{
#pragma unroll
  for (int i = 0; i < 2; ++i) {
    const int s   = wv * 128 + i * 64 + lane;
    const int row = s >> 2;
    const int gc  = ((s & 3) ^ ((row >> 1) & 3)) * 8;
    __builtin_amdgcn_global_load_lds(
        (const __attribute__((address_space(1))) void*)(src + (size_t)row * K + gc),
        (__attribute__((address_space(3))) void*)(ldst + ((wv * 128 + i * 64) << 3)),
        16, 0, 0);
  }
}

// ---------------------------------------------------------------------------
// Unified 128x128 MFMA GEMM engine (r10-proven). 4 waves, BK=32, KU tiles per
// phase, DEPTH-deep circular dbuf with counted vmcnt.
//  ORD0: 1-pass;  ORD1: fp16 scaled-residual 2-plane, 3 passes.
// OUTM: 0=f32, 1=2 fp16 planes, 2=f32+2 fp16 planes, 3=bf16,
//       4=bf16 transposed ([N][M], stride ldc),
//       5=2 fp16 planes + fused row-argmax (packed-key atomicMax into keys;
//         row = z*1024+m, key = mono(x)<<32 | (255-n); np first-max order).
// ---------------------------------------------------------------------------
template<int ORD, int KU, int DEPTH, int OUTM, bool BIAS, bool RELU, bool F16IN>
__global__ __launch_bounds__(256)
void gke(const unsigned short* __restrict__ A0, const unsigned short* __restrict__ A1,
         const unsigned short* __restrict__ B0, const unsigned short* __restrict__ B1,
         const float* __restrict__ bias,
         float* __restrict__ Cf, unsigned short* __restrict__ O0,
         unsigned short* __restrict__ O1, unsigned long long* __restrict__ keys,
         int K, int ldc, long sA, long sB, long sC, long sBias, float scale)
{
  constexpr int NP   = ORD + 1;
  constexpr int NT   = 2 * NP;
  constexpr int TPP  = KU * NT;
  constexpr int LPP  = TPP * 2;
  static_assert(DEPTH == 2 || DEPTH == 4, "DEPTH in {2,4}");
  static_assert(LPP == 4 || LPP == 8 || LPP == 16, "vmcnt literals");
  extern __shared__ __align__(16) unsigned short lds[];

  const int tid  = threadIdx.x;
  const int wv   = tid >> 6, lane = tid & 63;
  const int wr   = wv >> 1,  wc   = wv & 1;
  const int cr   = lane & 15, cg  = lane >> 4;
  const int bm   = blockIdx.x * 128, bn = blockIdx.y * 128;

  const size_t zA = (size_t)blockIdx.z * (size_t)sA;
  const size_t zB = (size_t)blockIdx.z * (size_t)sB;
  const size_t zC = (size_t)blockIdx.z * (size_t)sC;
  const size_t zBias = (size_t)blockIdx.z * (size_t)sBias;

  const unsigned short* srcs[NT];
  srcs[0] = A0 + zA + (size_t)bm * K;
  if (NP == 2) srcs[1] = A1 + zA + (size_t)bm * K;
  srcs[NP + 0] = B0 + zB + (size_t)bn * K;
  if (NP == 2) srcs[NP + 1] = B1 + zB + (size_t)bn * K;

  f32x4 acc0[4][4], acc1[4][4];
#pragma unroll
  for (int i = 0; i < 4; ++i)
#pragma unroll
    for (int j = 0; j < 4; ++j)
#pragma unroll
      for (int r = 0; r < 4; ++r) {
        acc0[i][j][r] = 0.f;
        if (ORD == 1) acc1[i][j][r] = 0.f;
      }

#define STAGE_PH(ph, buf)                                                       \
  {                                                                             \
    _Pragma("unroll")                                                           \
    for (int u = 0; u < KU; ++u)                                                \
      _Pragma("unroll")                                                         \
      for (int t = 0; t < NT; ++t)                                              \
        stage_tile(srcs[t] + ((ph) * KU + u) * 32, K,                           \
                   lds + (size_t)((buf) * TPP + u * NT + t) * 4096, wv, lane);  \
  }
#define LOADA(u, pa)                                                            \
  {                                                                             \
    _Pragma("unroll")                                                           \
    for (int f = 0; f < 4; ++f) {                                               \
      const int ra = wr * 64 + f * 16 + cr;                                     \
      af[f] = *(const bf16x8*)&lb[(size_t)((u) * NT + (pa)) * 4096 +            \
                                  (ra * 4 + (cg ^ ((ra >> 1) & 3))) * 8];       \
    }                                                                           \
  }
#define DOPB(u, pb, ACC)                                                        \
  {                                                                             \
    bf16x8 bfr[4];                                                              \
    _Pragma("unroll")                                                           \
    for (int f = 0; f < 4; ++f) {                                               \
      const int rb = wc * 64 + f * 16 + cr;                                     \
      bfr[f] = *(const bf16x8*)&lb[(size_t)((u) * NT + NP + (pb)) * 4096 +      \
                                   (rb * 4 + (cg ^ ((rb >> 1) & 3))) * 8];      \
    }                                                                           \
    _Pragma("unroll")                                                           \
    for (int i = 0; i < 4; ++i)                                                 \
      _Pragma("unroll")                                                         \
      for (int j = 0; j < 4; ++j) {                                             \
        if constexpr (F16IN)                                                    \
          ACC[i][j] = __builtin_amdgcn_mfma_f32_16x16x32_f16(                   \
              __builtin_bit_cast(f16x8, af[i]), __builtin_bit_cast(f16x8, bfr[j]), \
              ACC[i][j], 0, 0, 0);                                              \
        else                                                                    \
          ACC[i][j] = __builtin_amdgcn_mfma_f32_16x16x32_bf16(af[i], bfr[j],    \
              ACC[i][j], 0, 0, 0);                                              \
      }                                                                         \
  }
#define COMPUTE_PH(buf)                                                         \
  {                                                                             \
    const unsigned short* lb = lds + (size_t)(buf) * TPP * 4096;                \
    bf16x8 af[4];                                                               \
    _Pragma("unroll")                                                           \
    for (int u = 0; u < KU; ++u) {                                              \
      if constexpr (ORD == 1) {                                                 \
        LOADA(u, 0); DOPB(u, 0, acc0); DOPB(u, 1, acc1);                        \
        LOADA(u, 1); DOPB(u, 0, acc1);                                          \
      } else {                                                                  \
        LOADA(u, 0); DOPB(u, 0, acc0);                                          \
      }                                                                         \
    }                                                                           \
  }

  const int nph = K / (32 * KU);
#pragma unroll
  for (int d = 0; d < DEPTH; ++d)
    if (d < nph) STAGE_PH(d, d);

  for (int ph = 0; ph < nph; ++ph) {
    const int rem = nph - 1 - ph;
    const int fut = rem < (DEPTH - 1) ? rem : (DEPTH - 1);
    if constexpr (LPP == 4) {
      if (fut >= 3)      asm volatile("s_waitcnt vmcnt(12)" ::: "memory");
      else if (fut == 2) asm volatile("s_waitcnt vmcnt(8)" ::: "memory");
      else if (fut == 1) asm volatile("s_waitcnt vmcnt(4)" ::: "memory");
      else               asm volatile("s_waitcnt vmcnt(0)" ::: "memory");
    } else if constexpr (LPP == 8) {
      if (fut >= 3)      asm volatile("s_waitcnt vmcnt(24)" ::: "memory");
      else if (fut == 2) asm volatile("s_waitcnt vmcnt(16)" ::: "memory");
      else if (fut == 1) asm volatile("s_waitcnt vmcnt(8)" ::: "memory");
      else               asm volatile("s_waitcnt vmcnt(0)" ::: "memory");
    } else {
      if (fut >= 1)      asm volatile("s_waitcnt vmcnt(16)" ::: "memory");
      else               asm volatile("s_waitcnt vmcnt(0)" ::: "memory");
    }
    __builtin_amdgcn_sched_barrier(0);
    __builtin_amdgcn_s_barrier();        // all waves' stores for buf landed
    COMPUTE_PH(ph & (DEPTH - 1));
    __builtin_amdgcn_s_barrier();        // all readers of buf done
    __builtin_amdgcn_sched_barrier(0);
    if (ph + DEPTH < nph) STAGE_PH(ph + DEPTH, ph & (DEPTH - 1));
  }
#undef STAGE_PH
#undef LOADA
#undef DOPB
#undef COMPUTE_PH

  // epilogue: C/D layout col = lane&15, row = 4*(lane>>4)+reg  [m89-verified]
  const float RS = 2.44140625e-4f;       // 1/4096
  float* CfB = Cf + zC;
  unsigned short* O0B = O0 + zC;
  unsigned short* O1B = O1 + zC;

  if constexpr (OUTM == 5) {
    // 2 fp16 planes + fused row-argmax (exact np.argmax order)
#pragma unroll
    for (int fm = 0; fm < 4; ++fm) {
      const int m0 = bm + wr * 64 + fm * 16 + 4 * cg;
      unsigned long long bk[4] = {0ull, 0ull, 0ull, 0ull};
#pragma unroll
      for (int fn = 0; fn < 4; ++fn) {
        const int n = bn + wc * 64 + fn * 16 + cr;
#pragma unroll
        for (int r = 0; r < 4; ++r) {
          const float x = (acc0[fm][fn][r] + acc1[fm][fn][r] * RS) * scale;
          unsigned short a, b;
          split2h(x, a, b);
          const size_t off = (size_t)(m0 + r) * ldc + n;
          O0B[off] = a; O1B[off] = b;
          const unsigned long long k =
              ((unsigned long long)fmono(x) << 32) | (unsigned)(255 - n);
          if (k > bk[r]) bk[r] = k;
        }
      }
#pragma unroll
      for (int r = 0; r < 4; ++r) {
        unsigned long long k = bk[r];
#pragma unroll
        for (int o = 1; o < 16; o <<= 1) {
          const unsigned long long ok =
              (unsigned long long)__shfl_xor((long long)k, o, 16);
          if (ok > k) k = ok;
        }
        if ((lane & 15) == 0)
          atomicMax(keys + (size_t)blockIdx.z * 1024 + (m0 + r), k);
      }
    }
    return;
  }

#pragma unroll
  for (int fm = 0; fm < 4; ++fm) {
#pragma unroll
    for (int fn = 0; fn < 4; ++fn) {
      const int n  = bn + wc * 64 + fn * 16 + cr;
      const int m0 = bm + wr * 64 + fm * 16 + 4 * cg;
      float bv = 0.f;
      if (BIAS) bv = bias[zBias + n];
      if (OUTM == 4) {
        u16x4 o;
#pragma unroll
        for (int r = 0; r < 4; ++r) {
          float x = acc0[fm][fn][r];
          if constexpr (ORD == 1) x += acc1[fm][fn][r] * RS;
          x = x * scale + bv;
          if (RELU) x = fmaxf(x, 0.f);
          o[r] = f2bf(x);
        }
        *(u16x4*)(O0B + (size_t)n * ldc + m0) = o;
      } else {
#pragma unroll
        for (int r = 0; r < 4; ++r) {
          float x = acc0[fm][fn][r];
          if constexpr (ORD == 1) x += acc1[fm][fn][r] * RS;
          x = x * scale + bv;
          if (RELU) x = fmaxf(x, 0.f);
          const size_t off = (size_t)(m0 + r) * ldc + n;
          if (OUTM == 0) CfB[off] = x;
          else if (OUTM == 3) O0B[off] = f2bf(x);
          else {
            unsigned short a, b;
            split2h(x, a, b);
            O0B[off] = a; O1B[off] = b;
            if (OUTM == 2) CfB[off] = x;
          }
        }
      }
    }
  }
}

// ---------------------------------------------------------------------------
// Masked softmax over rows of length 1024 for a 512-row i-half; emits
// P^T[b][j][i_global] bf16. Lg layout [b][512][1024].
// Argmax indices decoded from packed keys: idx = 255 - (key & 0xFFFFFFFF).
// ---------------------------------------------------------------------------
__global__ __launch_bounds__(256)
void softmax_T(const float* __restrict__ Lg, const unsigned long long* __restrict__ keysA,
               const unsigned long long* __restrict__ keysB,
               unsigned short* __restrict__ PT, int ihalf)
{
  __shared__ int bj[1024];
  __shared__ unsigned short tile[1024 * 17];
  const int tid = threadIdx.x;
  const int i0  = blockIdx.x * 16;          // 0..511
  const int b   = blockIdx.y;
  const int r   = tid >> 4;
  const int l16 = tid & 15;

  for (int j = tid; j < 1024; j += 256)
    bj[j] = 255 - (int)(keysB[(b << 10) + j] & 0xFFFFFFFFull);
  __syncthreads();

  const int ai = 255 - (int)(keysA[(b << 10) + (ihalf << 9) + i0 + r] & 0xFFFFFFFFull);
  const float* Lr = Lg + ((size_t)b * 512 + i0 + r) * 1024;
  const int jb = l16 * 64;

  float x[64];
  float mx = -3.0e38f;
#pragma unroll
  for (int q = 0; q < 16; ++q) {
    f32x4 f = *(const f32x4*)(Lr + jb + (q << 2));
#pragma unroll
    for (int u = 0; u < 4; ++u) {
      const int j = jb + (q << 2) + u;
      float t = f[u];
      if (bj[j] != ai) t -= 1e6f;
      x[(q << 2) + u] = t;
      mx = fmaxf(mx, t);
    }
  }
#pragma unroll
  for (int off = 8; off >= 1; off >>= 1) mx = fmaxf(mx, __shfl_xor(mx, off));
  float s = 0.f;
#pragma unroll
  for (int k = 0; k < 64; ++k) { float e = expf(x[k] - mx); x[k] = e; s += e; }
#pragma unroll
  for (int off = 8; off >= 1; off >>= 1) s += __shfl_xor(s, off);
  const float inv = 1.f / s;

#pragma unroll
  for (int k = 0; k < 64; ++k)
    tile[(jb + k) * 17 + r] = f2bf(x[k] * inv);
  __syncthreads();

  for (int j = tid; j < 1024; j += 256) {
    const unsigned short* tp = &tile[j * 17];
    unsigned int w[8];
#pragma unroll
    for (int q = 0; q < 8; ++q)
      w[q] = (unsigned int)tp[2 * q] | ((unsigned int)tp[2 * q + 1] << 16);
    const size_t off = ((size_t)b << 20) + ((size_t)j << 10) + (ihalf << 9) + i0;
    unsigned int* dst = (unsigned int*)(PT + off);
    *(uint4*)dst       = make_uint4(w[0], w[1], w[2], w[3]);
    *((uint4*)dst + 1) = make_uint4(w[4], w[5], w[6], w[7]);
  }
}

// ---------------------------------------------------------------------------
extern "C" void kernel_launch(void* const* d_in, const int* in_sizes, int n_in,
                              void* d_out, int out_size, void* d_ws, size_t ws_size,
                              hipStream_t stream)
{
  (void)in_sizes; (void)n_in; (void)out_size; (void)ws_size;

  const float* tok  = (const float*)d_in[0];
  const float* supp = (const float*)d_in[1];
  const float* qry  = (const float*)d_in[2];
  const float* W_qa = (const float*)d_in[3];
  const float* b_qa = (const float*)d_in[4];
  const float* W_ks = (const float*)d_in[5];
  const float* b_ks = (const float*)d_in[6];
  const float* W_ka = (const float*)d_in[7];
  const float* b_ka = (const float*)d_in[8];
  const float* W_vs = (const float*)d_in[9];
  const float* b_vs = (const float*)d_in[10];
  const float* W_f1 = (const float*)d_in[11];
  const float* b_f1 = (const float*)d_in[12];
  const float* W_f2 = (const float*)d_in[13];
  const float* b_f2 = (const float*)d_in[14];

  // r10-proven engine configs; kScore gains fused argmax (OUTM=5, no fp32 out)
  auto kProj  = &gke<1,1,2,1,true ,false,true >;   // 64 KB, vmcnt(8)
  auto kScore = &gke<1,2,2,5,false,false,true >;   // 128 KB, vmcnt(16)
  auto kLogit = &gke<1,1,2,0,false,false,true >;   // 64 KB
  auto kVsT   = &gke<0,1,2,4,true ,false,true >;   // 32 KB fp16 1-pass
  auto kPV    = &gke<0,1,2,3,false,false,false>;   // 32 KB bf16
  auto kFFN1  = &gke<0,1,2,3,true ,true ,false>;   // 32 KB bf16
  auto kFFN2  = &gke<0,1,2,0,true ,false,false>;   // 32 KB bf16
  hipFuncSetAttribute((const void*)kProj,  hipFuncAttributeMaxDynamicSharedMemorySize, 65536);
  hipFuncSetAttribute((const void*)kScore, hipFuncAttributeMaxDynamicSharedMemorySize, 131072);
  hipFuncSetAttribute((const void*)kLogit, hipFuncAttributeMaxDynamicSharedMemorySize, 65536);
  hipFuncSetAttribute((const void*)kVsT,   hipFuncAttributeMaxDynamicSharedMemorySize, 32768);
  hipFuncSetAttribute((const void*)kPV,    hipFuncAttributeMaxDynamicSharedMemorySize, 32768);
  hipFuncSetAttribute((const void*)kFFN1,  hipFuncAttributeMaxDynamicSharedMemorySize, 32768);
  hipFuncSetAttribute((const void*)kFFN2,  hipFuncAttributeMaxDynamicSharedMemorySize, 32768);

  char* W = (char*)d_ws;
  constexpr size_t MiB = 1048576;
  auto U = [&](double off) { return (unsigned short*)(W + (size_t)(off * MiB)); };
  auto F = [&](double off) { return (float*)(W + (size_t)(off * MiB)); };
  auto KY = [&](double off) { return (unsigned long long*)(W + (size_t)(off * MiB)); };

  // lifetimes (MiB): same audited layout as r10; QTF/SAF fp32 buffers removed
  // (argmax fused). keys at 148.5/148.75 (within proven ws range).
  const double oTOK0=0, oTOK1=4, oSUP0=0, oPT=0;
  const double oWQAT=16, oWKAT=17.5, oWKST=19, oWVST=20.5;
  const double oQA0=22, oQA1=26, oDEC=32, oKA0=34, oKA1=38;
  const double oQRY0=46, oQRY1=62, oQTP0=46, oQTP1=54;
  const double oSUP1=62, oVST=62, oSAP0=78, oSAP1=86;
  const double oQQ0=94, oQQ1=110, oLG=94, oMID=62;
  const double oWF1=142, oWF2=143.5, oBIA=148, oKEYB=148.5, oKEYA=148.75;
  const double hP = 0.5;  // one 512x512 16-bit plane = 0.5 MiB

  const dim3 B256(256), BW(32, 8);
  float* dummyF = F(oLG);
  unsigned short* dummyU = U(oLG);
  unsigned long long* dummyK = KY(oLG);

  // S0: stage qa/ka biases adjacently; zero argmax key buffers (128 KB each)
  hipMemcpyAsync(W + (size_t)(oBIA * MiB), b_qa, 2048, hipMemcpyDeviceToDevice, stream);
  hipMemcpyAsync(W + (size_t)(oBIA * MiB) + 2048, b_ka, 2048, hipMemcpyDeviceToDevice, stream);
  hipMemsetAsync(KY(oKEYB), 0, kBS * kHW * 8, stream);
  hipMemsetAsync(KY(oKEYA), 0, kBS * kHW * 8, stream);

  // S1: weight + tok splits
  split_wT2h<<<dim3(16,16), BW, 0, stream>>>(W_qa, U(oWQAT), U(oWQAT+hP), 512, 512);
  split_wT2h<<<dim3(16,16), BW, 0, stream>>>(W_ka, U(oWKAT), U(oWKAT+hP), 512, 512);
  split_wT2h<<<dim3(16,16), BW, 0, stream>>>(W_ks, U(oWKST), U(oWKST+hP), 512, 512);
  split_wT1<true><<<dim3(16,16), BW, 0, stream>>>(W_vs, U(oWVST), 512, 512);
  split_act2h<<<dim3(2048), B256, 0, stream>>>((const f32x4*)tok, (u16x4*)U(oTOK0), (u16x4*)U(oTOK1), 524288);
  // S2: qa|ka merged projection: z=0 -> {WQAT,b_qa,qaP}, z=1 -> {WKAT,b_ka,kaP}
  kProj<<<dim3(32,4,2), B256, 65536, stream>>>(
      U(oTOK0),U(oTOK1), U(oWQAT),U(oWQAT+hP),
      F(oBIA), dummyF, U(oQA0),U(oQA1), dummyK, 512, 512, 0, 786432, 6291456, 512, 1.f);
  // S3: qry split
  split_act2h<<<dim3(8192), B256, 0, stream>>>((const f32x4*)qry, (u16x4*)U(oQRY0), (u16x4*)U(oQRY1), 2097152);
  // S4: qq projection
  kProj<<<dim3(128,4,1), B256, 65536, stream>>>(
      U(oQRY0),U(oQRY1), U(oWQAT),U(oWQAT+hP),
      b_qa, dummyF, U(oQQ0),U(oQQ1), dummyK, 512, 512, 0,0,0,0, 1.f);
  // S5: qt score = qq . ka^T / 8  -> 2 fp16 planes + fused argmax (keysB)
  kScore<<<dim3(8,2,16), B256, 131072, stream>>>(
      U(oQQ0),U(oQQ1), U(oKA0),U(oKA1),
      nullptr, dummyF, U(oQTP0),U(oQTP1), KY(oKEYB), 512, 256,
      524288, 131072, 262144, 0, 0.125f);
  // S6: supp split (plane0 over dead tok region; plane1 over dead qry plane1)
  split_act2h<<<dim3(8192), B256, 0, stream>>>((const f32x4*)supp, (u16x4*)U(oSUP0), (u16x4*)U(oSUP1), 2097152);
  // S7: ks projection (out over dead qq planes), then vs^T (reads supp plane0)
  kProj<<<dim3(128,4,1), B256, 65536, stream>>>(
      U(oSUP0),U(oSUP1), U(oWKST),U(oWKST+hP),
      b_ks, dummyF, U(oQQ0),U(oQQ1), dummyK, 512, 512, 0,0,0,0, 1.f);
  kVsT<<<dim3(8,4,16), B256, 32768, stream>>>(
      U(oSUP0),dummyU, U(oWVST),dummyU,
      b_vs, dummyF, U(oVST),dummyU, dummyK, 512, 1024,
      524288, 0, 524288, 0, 1.f);
  // S8: sa score = ks . qa^T / 8  -> 2 fp16 planes + fused argmax (keysA)
  kScore<<<dim3(8,2,16), B256, 131072, stream>>>(
      U(oQQ0),U(oQQ1), U(oQA0),U(oQA1),
      nullptr, dummyF, U(oSAP0),U(oSAP1), KY(oKEYA), 512, 256,
      524288, 131072, 262144, 0, 0.125f);
  // FFN weight splits (bf16, stable through the end)
  split_wT1<false><<<dim3(16,48), BW, 0, stream>>>(W_f1, U(oWF1), 512, 1536);
  split_wT1<false><<<dim3(48,16), BW, 0, stream>>>(W_f2, U(oWF2), 1536, 512);
  // S9/S10: logits halves (fp16 2-plane 3-pass, K=256) + masked softmax -> P^T
  for (int h = 0; h < 2; ++h) {
    kLogit<<<dim3(4,8,16), B256, 65536, stream>>>(
        U(oSAP0) + (size_t)h*512*256, U(oSAP1) + (size_t)h*512*256,
        U(oQTP0), U(oQTP1),
        nullptr, F(oLG), dummyU,dummyU, dummyK, 256, 1024,
        262144, 262144, 524288, 0, 1.f);
    softmax_T<<<dim3(32,16), B256, 0, stream>>>(F(oLG), KY(oKEYA), KY(oKEYB), U(oPT), h);
  }
  // S11: dec = P^T . vs   (A=PT [j][i], B=vsT [c][i], bf16, K=1024)
  kPV<<<dim3(8,4,16), B256, 32768, stream>>>(
      U(oPT),dummyU, U(oVST),dummyU,
      nullptr, dummyF, U(oDEC),dummyU, dummyK, 1024, 512,
      1048576, 524288, 524288, 0, 1.f);
  // S12: FFN1 = relu(dec @ W_f1 + b1) -> bf16
  kFFN1<<<dim3(128,12,1), B256, 32768, stream>>>(
      U(oDEC),dummyU, U(oWF1),dummyU,
      b_f1, dummyF, U(oMID),dummyU, dummyK, 512, 1536, 0,0,0,0, 1.f);
  // S13: FFN2 = mid @ W_f2 + b2 -> d_out fp32 (K=1536)
  kFFN2<<<dim3(128,4,1), B256, 32768, stream>>>(
      U(oMID),dummyU, U(oWF2),dummyU,
      b_f2, (float*)d_out, dummyU,dummyU, dummyK, 1536, 512, 0,0,0,0, 1.f);
}